// Round 1
// baseline (1060.477 us; speedup 1.0000x reference)
//
#include <hip/hip_runtime.h>
#include <math.h>

#define NGRAPH 128

// ---------------- degree / CSR build ----------------

__global__ void count_k(const int* __restrict__ dst, int* __restrict__ counts, int E) {
    int e = blockIdx.x * blockDim.x + threadIdx.x;
    if (e < E) atomicAdd(&counts[dst[e]], 1);
}

__global__ void dis_k(const int* __restrict__ counts, float* __restrict__ dis, int n) {
    int i = blockIdx.x * blockDim.x + threadIdx.x;
    if (i < n) dis[i] = rsqrtf((float)counts[i] + 1.0f);  // +1 self-loop; deg>=1 always
}

// single-block exclusive scan of counts[0..n) -> offsets[0..n]; also turns
// counts[] into the cursor array (init = offsets) for the fill pass.
__global__ void scan_k(int* counts, int* __restrict__ offsets, int n) {
    __shared__ int lsum[1024];
    int t = threadIdx.x;
    int ch = (n + 1023) / 1024;
    int b = t * ch;
    int e = min(b + ch, n);
    int s = 0;
    for (int i = b; i < e; ++i) s += counts[i];
    lsum[t] = s;
    __syncthreads();
    // inclusive Hillis-Steele scan over 1024 partials
    for (int off = 1; off < 1024; off <<= 1) {
        int v = (t >= off) ? lsum[t - off] : 0;
        __syncthreads();
        lsum[t] += v;
        __syncthreads();
    }
    int run = lsum[t] - s;  // exclusive prefix for this thread's range
    for (int i = b; i < e; ++i) {
        int c = counts[i];
        offsets[i] = run;
        counts[i] = run;   // cursor init
        run += c;
    }
    if (t == 1023) offsets[n] = lsum[1023];
}

__global__ void fill_k(const int* __restrict__ src, const int* __restrict__ dst,
                       int* cursor, int* __restrict__ csr, int E) {
    int e = blockIdx.x * blockDim.x + threadIdx.x;
    if (e < E) {
        int d = dst[e];
        int p = atomicAdd(&cursor[d], 1);
        csr[p] = src[e];
    }
}

// ---------------- dense layers ----------------

// t0 = x @ W1   ([n,3] @ [3,64])
__global__ void mm1_k(const float* __restrict__ x, const float* __restrict__ W1,
                      float* __restrict__ t0, int n) {
    __shared__ float w[3 * 64];
    int tid = threadIdx.x;
    if (tid < 192) w[tid] = W1[tid];
    __syncthreads();
    int g = blockIdx.x * blockDim.x + tid;
    int node = g >> 6, c = g & 63;
    if (node < n) {
        float v = x[node * 3 + 0] * w[c]
                + x[node * 3 + 1] * w[64 + c]
                + x[node * 3 + 2] * w[128 + c];
        t0[node * 64 + c] = v;
    }
}

// t1 = relu(aggIn) @ W2   ([n,64] @ [64,64]); W2 staged in LDS; wave per node
__global__ void mm2_k(const float* __restrict__ aggIn, const float* __restrict__ W2,
                      float* __restrict__ t1, int n) {
    __shared__ float w[64 * 64];
    __shared__ float hrow[4][64];
    int tid = threadIdx.x;
    for (int i = tid; i < 4096; i += 256) w[i] = W2[i];
    int nl = tid >> 6, j = tid & 63;
    int node = blockIdx.x * 4 + nl;
    float h = (node < n) ? fmaxf(aggIn[node * 64 + j], 0.0f) : 0.0f;
    __syncthreads();
    hrow[nl][j] = h;
    __syncthreads();
    if (node < n) {
        float acc = 0.0f;
#pragma unroll
        for (int k = 0; k < 64; k += 4) {
            float4 h4 = *(const float4*)&hrow[nl][k];
            acc += h4.x * w[(k + 0) * 64 + j];
            acc += h4.y * w[(k + 1) * 64 + j];
            acc += h4.z * w[(k + 2) * 64 + j];
            acc += h4.w * w[(k + 3) * 64 + j];
        }
        t1[node * 64 + j] = acc;
    }
}

// ---------------- aggregation (gather over CSR-by-dst) ----------------

// agg[n,:] = bias + dis[n]^2 * t[n,:] + sum_{s in in(n)} dis[s]*dis[n] * t[s,:]
// one 64-lane wave per node, lane = channel
__global__ void gather_k(const float* __restrict__ t, const int* __restrict__ off,
                         const int* __restrict__ csr, const float* __restrict__ dis,
                         const float* __restrict__ bias, float* __restrict__ agg, int n) {
    int g = blockIdx.x * blockDim.x + threadIdx.x;
    int node = g >> 6, lane = g & 63;
    if (node >= n) return;
    float dn = dis[node];
    float acc = t[node * 64 + lane] * (dn * dn) + bias[lane];
    int b = off[node], e = off[node + 1];
    int i = b;
    for (; i + 4 <= e; i += 4) {
        int s0 = csr[i], s1 = csr[i + 1], s2 = csr[i + 2], s3 = csr[i + 3];
        float w0 = dis[s0] * dn, w1 = dis[s1] * dn, w2 = dis[s2] * dn, w3 = dis[s3] * dn;
        acc += t[s0 * 64 + lane] * w0;
        acc += t[s1 * 64 + lane] * w1;
        acc += t[s2 * 64 + lane] * w2;
        acc += t[s3 * 64 + lane] * w3;
    }
    for (; i < e; ++i) {
        int s = csr[i];
        acc += t[s * 64 + lane] * (dis[s] * dn);
    }
    agg[node * 64 + lane] = acc;  // relu applied by consumer
}

// ---------------- pooling + head ----------------

__device__ inline int lower_bound_i(const int* a, int n, int key) {
    int lo = 0, hi = n;
    while (lo < hi) {
        int mid = (lo + hi) >> 1;
        if (a[mid] < key) lo = mid + 1; else hi = mid;
    }
    return lo;
}

// batch is sorted: one block per graph, binary-search the boundaries
__global__ void pool_k(const float* __restrict__ agg2, const int* __restrict__ batch,
                       float* __restrict__ pooled, int n) {
    int g = blockIdx.x;
    int start = lower_bound_i(batch, n, g);
    int end   = lower_bound_i(batch, n, g + 1);
    int wid = threadIdx.x >> 6, lane = threadIdx.x & 63;
    float acc = 0.0f;
    for (int i = start + wid; i < end; i += 4)
        acc += fmaxf(agg2[i * 64 + lane], 0.0f);
    __shared__ float red[4][64];
    red[wid][lane] = acc;
    __syncthreads();
    if (threadIdx.x < 64) {
        float s = red[0][lane] + red[1][lane] + red[2][lane] + red[3][lane];
        float cnt = (float)(end - start);
        pooled[g * 64 + lane] = s / fmaxf(cnt, 1.0f);
    }
}

__global__ void head_k(const float* __restrict__ pooled, const float* __restrict__ Wl,
                       const float* __restrict__ bl, float* __restrict__ out) {
    int g = blockIdx.x, t = threadIdx.x;
    __shared__ float p[64];
    __shared__ float logit[8];
    p[t] = pooled[g * 64 + t];
    __syncthreads();
    if (t < 6) {
        float a = bl[t];
        for (int k = 0; k < 64; ++k) a += p[k] * Wl[k * 6 + t];
        logit[t] = a;
    }
    __syncthreads();
    if (t == 0) {
        float m = logit[0];
        for (int j = 1; j < 6; ++j) m = fmaxf(m, logit[j]);
        float s = 0.0f;
        for (int j = 0; j < 6; ++j) s += expf(logit[j] - m);
        float lse = m + logf(s);
        for (int j = 0; j < 6; ++j) out[g * 6 + j] = logit[j] - lse;
    }
}

// ---------------- launch ----------------

extern "C" void kernel_launch(void* const* d_in, const int* in_sizes, int n_in,
                              void* d_out, int out_size, void* d_ws, size_t ws_size,
                              hipStream_t stream) {
    const float* x     = (const float*)d_in[0];
    const int*   ei    = (const int*)d_in[1];
    const int*   batch = (const int*)d_in[2];
    const float* W1    = (const float*)d_in[3];
    const float* b1    = (const float*)d_in[4];
    const float* W2    = (const float*)d_in[5];
    const float* b2    = (const float*)d_in[6];
    const float* Wl    = (const float*)d_in[7];
    const float* bl    = (const float*)d_in[8];

    int n = in_sizes[0] / 3;
    int E = in_sizes[1] / 2;
    const int* src = ei;
    const int* dst = ei + E;

    char* ws = (char*)d_ws;
    size_t o = 0;
    auto alloc = [&](size_t bytes) -> void* {
        void* p = ws + o;
        o += (bytes + 255) & ~(size_t)255;
        return p;
    };
    int*   counts  = (int*)alloc((size_t)n * 4);        // becomes cursor after scan
    int*   offsets = (int*)alloc((size_t)(n + 1) * 4);
    float* dis     = (float*)alloc((size_t)n * 4);
    int*   csr     = (int*)alloc((size_t)E * 4);
    float* t       = (float*)alloc((size_t)n * 64 * 4);
    float* agg     = (float*)alloc((size_t)n * 64 * 4);
    float* pooled  = (float*)alloc((size_t)NGRAPH * 64 * 4);
    float* out = (float*)d_out;

    hipMemsetAsync(counts, 0, (size_t)n * 4, stream);
    count_k<<<(E + 255) / 256, 256, 0, stream>>>(dst, counts, E);
    dis_k<<<(n + 255) / 256, 256, 0, stream>>>(counts, dis, n);
    scan_k<<<1, 1024, 0, stream>>>(counts, offsets, n);
    fill_k<<<(E + 255) / 256, 256, 0, stream>>>(src, dst, counts, csr, E);

    mm1_k<<<(n * 64 + 255) / 256, 256, 0, stream>>>(x, W1, t, n);
    gather_k<<<(n * 64 + 255) / 256, 256, 0, stream>>>(t, offsets, csr, dis, b1, agg, n);
    mm2_k<<<(n + 3) / 4, 256, 0, stream>>>(agg, W2, t, n);
    gather_k<<<(n * 64 + 255) / 256, 256, 0, stream>>>(t, offsets, csr, dis, b2, agg, n);

    pool_k<<<NGRAPH, 256, 0, stream>>>(agg, batch, pooled, n);
    head_k<<<NGRAPH, 64, 0, stream>>>(pooled, Wl, bl, out);
}